// Round 14
// baseline (123.467 us; speedup 1.0000x reference)
//
#include <hip/hip_runtime.h>

typedef unsigned short u16;
typedef unsigned int u32;
typedef unsigned long long u64;
typedef __attribute__((ext_vector_type(8))) short short8;
typedef __attribute__((ext_vector_type(4))) float f32x4;

#define B_ 2
#define T_ 2048
#define H_ 16
#define DK_ 64
#define QSCALE 0.18033688011112042f  // 0.125 * log2(e)

__device__ __forceinline__ u16 f2bf(float f){
  unsigned u = __float_as_uint(f);
  return (u16)((u + 0x7fffu + ((u >> 16) & 1u)) >> 16);
}

__device__ __forceinline__ u32 cvtpk(float lo, float hi){
  u32 r;
  asm("v_cvt_pk_bf16_f32 %0, %1, %2" : "=v"(r) : "v"(lo), "v"(hi));
  return r;
}

// 2^x via the compiler's fast-exp path (raw inline-asm v_exp_f32 lacks the
// TRANS-op wait-state and corrupts dependent reads — round-7's failure).
#define EXP2(x) __expf(0.6931471805599453f * (x))

// pack two f32x4 p-vectors into one bf16 A-fragment (8 elems)
__device__ __forceinline__ short8 pack8(const f32x4 a, const f32x4 b){
  union { u32 u[4]; short8 s; } t;
  t.u[0] = cvtpk(a[0], a[1]); t.u[1] = cvtpk(a[2], a[3]);
  t.u[2] = cvtpk(b[0], b[1]); t.u[3] = cvtpk(b[2], b[3]);
  return t.s;
}

#if defined(__has_builtin)
#if __has_builtin(__builtin_amdgcn_global_load_lds)
#define HAS_GLLDS 1
#endif
#endif

#ifdef HAS_GLLDS
__device__ __forceinline__ void gl_lds16(const u16* g, u16* l){
  __builtin_amdgcn_global_load_lds(
      (__attribute__((address_space(1))) void*)(void*)g,
      (__attribute__((address_space(3))) void*)(void*)l, 16, 0, 0);
}
__device__ __forceinline__ void wait_vm3(){ asm volatile("s_waitcnt vmcnt(3)" ::: "memory"); }
__device__ __forceinline__ void wait_vm0(){ asm volatile("s_waitcnt vmcnt(0)" ::: "memory"); }
__device__ __forceinline__ void pipe_bar(){
  asm volatile("" ::: "memory");
  __builtin_amdgcn_s_barrier();
  asm volatile("" ::: "memory");
}
#else
__device__ __forceinline__ void wait_vm3(){}
__device__ __forceinline__ void wait_vm0(){}
__device__ __forceinline__ void pipe_bar(){ __syncthreads(); }
#endif

// ---------------- fused fp32 -> bf16 convert (x + 4 weights) ----------------
__global__ __launch_bounds__(256) void conv_all(
    const float* __restrict__ x, const float* __restrict__ wq, const float* __restrict__ wk,
    const float* __restrict__ wv, const float* __restrict__ wo,
    u16* __restrict__ xb, u16* __restrict__ wqb, u16* __restrict__ wkb,
    u16* __restrict__ wvb, u16* __restrict__ wob)
{
  int gid = blockIdx.x * 256 + threadIdx.x;
  const float* src; u16* dst; int off;
  if (gid < 1048576){ src = x; dst = xb; off = gid; }
  else {
    int t = gid - 1048576; int s = t >> 18; off = t & 262143;
    src = (s==0)?wq:((s==1)?wk:((s==2)?wv:wo));
    dst = (s==0)?wqb:((s==1)?wkb:((s==2)?wvb:wob));
  }
  float4 v = ((const float4*)src)[off];
  u64 r = (u64)f2bf(v.x) | ((u64)f2bf(v.y)<<16) | ((u64)f2bf(v.z)<<32) | ((u64)f2bf(v.w)<<48);
  ((u64*)dst)[off] = r;
}

// ---------------- GEMM: 128m x 64n tile, BK=32, 3-buf counted-vmcnt ----------------
// Geometry change ONLY vs r9's proven gemm_k5 (same pipeline/waits/swizzle):
// smaller tile -> QKV grid 1536 = 4 blocks/CU (LDS 36KB), O grid 512 = 2/CU.
// Mechanism: m114 wave-overlap — more resident independent blocks absorb the
// per-tile stage-drain stalls that dominate this loop (~70%).
// 4 waves, each 32m x 64n: acc[2][4]. 3 gl_lds per wave per stage (A:2, B:1).
// QKV=1: fused Q/K/V (grid.x=48); Q pre-scaled, K col-swizzled. QKV=0: fp32 out.
template<int QKV>
__global__ __launch_bounds__(256, 4) void gemm_k6(
    const u16* __restrict__ A,
    const u16* __restrict__ W0, const u16* __restrict__ W1, const u16* __restrict__ W2,
    const float* __restrict__ b0, const float* __restrict__ b1, const float* __restrict__ b2,
    void* __restrict__ o0, void* __restrict__ o1, void* __restrict__ o2)
{
  __shared__ u16 As[3 * 4096];   // 128 rows x 32
  __shared__ u16 Bs[3 * 2048];   // 64 rows x 32
  const int tid = threadIdx.x;
  const int sel = QKV ? (blockIdx.x >> 4) : 0;
  const int n0 = (blockIdx.x & 15) * 64;
  const int m0 = blockIdx.y * 128;
  const u16* Bw = (sel==0)?W0:((sel==1)?W1:W2);
  const float* bias = (sel==0)?b0:((sel==1)?b1:b2);
  const int w = tid>>6, l = tid&63;
  const int lr = l&15, lg = l>>4;
  const int wm = 32 * w;                      // wave's 32-row m slice
  // staging source: row l>>2 within 16-row chunk, SWIZZLED 16B col chunk (r9-proven)
  const int scol = ((l & 3) ^ ((l >> 3) & 3)) * 8;
  const u16* Ab = A  + (size_t)m0*1024 + (size_t)(l>>2)*1024 + scol;
  const u16* Bb = Bw + (size_t)n0*1024 + (size_t)(l>>2)*1024 + scol;
  const int rsw = (lr >> 1) & 3;              // read-side swizzle
  f32x4 acc[2][4] = {};

  auto STAGE = [&](int t, int pb){
#pragma unroll
    for (int i = 0; i < 2; ++i){
      int c = w*2 + i;                        // A chunks 0..7 (16 rows each)
#ifdef HAS_GLLDS
      gl_lds16(Ab + (size_t)(16*c)*1024 + t*32, &As[pb*4096 + c*512]);
#else
      *(uint4*)&As[pb*4096 + c*512 + l*8] = *(const uint4*)(Ab + (size_t)(16*c)*1024 + t*32);
#endif
    }
#ifdef HAS_GLLDS
    gl_lds16(Bb + (size_t)(16*w)*1024 + t*32, &Bs[pb*2048 + w*512]);  // B chunk w
#else
    *(uint4*)&Bs[pb*2048 + w*512 + l*8] = *(const uint4*)(Bb + (size_t)(16*w)*1024 + t*32);
#endif
  };

  STAGE(0, 0); STAGE(1, 1);
  wait_vm3();            // tile 0 landed (3 newest = tile 1 may fly)
  pipe_bar();
  for (int it = 0; it < 32; ++it){
    const int pb = it % 3;
    if (it < 30) STAGE(it + 2, (it + 2) % 3);
    short8 af[2], bf[4];
#pragma unroll
    for (int mi=0;mi<2;++mi) af[mi] = *(const short8*)&As[pb*4096 + (wm+16*mi+lr)*32 + 8*(lg ^ rsw)];
#pragma unroll
    for (int ni=0;ni<4;++ni) bf[ni] = *(const short8*)&Bs[pb*2048 + (16*ni+lr)*32 + 8*(lg ^ rsw)];
#pragma unroll
    for (int mi=0;mi<2;++mi)
#pragma unroll
      for (int ni=0;ni<4;++ni)
        acc[mi][ni] = __builtin_amdgcn_mfma_f32_16x16x32_bf16(af[mi], bf[ni], acc[mi][ni], 0,0,0);
    if (it < 31){
      if (it < 30) wait_vm3();   // tile it+1 landed, tile it+2 still in flight
      else         wait_vm0();   // tail drain
      pipe_bar();
    }
  }

  float bv[4];
#pragma unroll
  for (int ni=0;ni<4;++ni) bv[ni] = bias[n0 + 16*ni + lr];
  void* C = QKV ? ((sel==0)?o0:((sel==1)?o1:o2)) : o0;
#pragma unroll
  for (int mi=0;mi<2;++mi)
#pragma unroll
    for (int r=0;r<4;++r){
      const int trow = m0 + wm + 16*mi + 4*lg + r;
#pragma unroll
      for (int ni=0;ni<4;++ni){
        float v = acc[mi][ni][r] + bv[ni];
        int n = n0 + 16*ni + lr;
        if (!QKV){
          ((float*)C)[(size_t)trow*1024 + n] = v;
        } else if (sel == 0){          // Q: pre-scale for exp2 softmax
          ((u16*)C)[(size_t)trow*1024 + n] = f2bf(v * QSCALE);
        } else if (sel == 1){          // K: bank-swizzle dk within each head
          int nsw = (n & ~63) | ((n & 63) ^ ((trow & 7) << 3));
          ((u16*)C)[(size_t)trow*1024 + nsw] = f2bf(v);
        } else {                       // V: natural
          ((u16*)C)[(size_t)trow*1024 + n] = f2bf(v);
        }
      }
    }
}

// ---------------- V transpose: V[B,T,H,DK] -> VT[B,H,DK,T], 128-chunk k-perm + XOR ----
// forward: k = 32ks+16lo+4c+r -> slot = 32ks+8c+4lo+r  (so swapped-QK^T P regs ARE
// the PV A-fragments). inverse: p -> k = 32(p>>5) + 16((p>>2)&1) + 4((p>>3)&3) + (p&3).
// phys: 8-elem chunk index XOR'ed with (d&7) for conflict-free LDS reads.
__global__ __launch_bounds__(256) void transpose_v128(const u16* __restrict__ V,
                                                      u16* __restrict__ VT){
  __shared__ u16 L[128 * 72];
  const int tid = threadIdx.x;
  const int tc = blockIdx.x, h = blockIdx.y, b = blockIdx.z;
#pragma unroll
  for (int p = 0; p < 4; ++p){
    int row = (tid >> 3) + 32 * p, g = tid & 7;
    *(uint4*)&L[row * 72 + g * 8] =
        *(const uint4*)(V + ((size_t)(b * T_ + tc * 128 + row) * H_ + h) * DK_ + g * 8);
  }
  __syncthreads();
#pragma unroll
  for (int p = 0; p < 4; ++p){
    int d = tid >> 2, g8 = (tid & 3) + 4 * p;
    union { uint4 u; u16 s[8]; } tv;
#pragma unroll
    for (int i = 0; i < 8; ++i){
      int pp = 8 * g8 + i;
      int tl = 32 * (pp >> 5) + 16 * ((pp >> 2) & 1) + 4 * ((pp >> 3) & 3) + (pp & 3);
      tv.s[i] = L[tl * 72 + d];
    }
    *(uint4*)(VT + ((size_t)(b * H_ + h) * DK_ + d) * T_ + tc * 128 + ((8 * g8) ^ ((d & 7) << 3))) = tv.u;
  }
}

// ---------------- causal flash attention (r9-proven attn_v7, verbatim) ----------------
// QBLK=128 (4 waves x 32 rows), KVBLK=128. Swapped QK^T, P in-register.
__global__ __launch_bounds__(256, 2) void attn_v7(
    const u16* __restrict__ Q, const u16* __restrict__ K,
    const u16* __restrict__ VT, u16* __restrict__ O)
{
  __shared__ u16 Ks[2][128 * 64];
  __shared__ u16 VTs[2][64 * 128];
  const int tid = threadIdx.x;
  const int w = tid >> 6, l = tid & 63;
  const int lr = l & 15, lg = l >> 4;
  const int h = blockIdx.y, b = blockIdx.z;
  const int qtb = (b == 0) ? blockIdx.x : (15 - blockIdx.x);
  const int q0 = qtb * 128;
  const int wrow0 = q0 + 32 * w;
  const size_t kbase = ((size_t)(b * T_) * H_ + h) * DK_;
  const size_t vbase = (size_t)(b * H_ + h) * DK_ * (size_t)T_;

  auto STAGE = [&](int kt, int pb){
#pragma unroll
    for (int p = 0; p < 4; ++p){
      int kr0 = 32 * w + 8 * p;
#ifdef HAS_GLLDS
      gl_lds16(K + kbase + (size_t)(kt * 128 + kr0 + (l >> 3)) * 1024 + (l & 7) * 8,
               &Ks[pb][kr0 * 64]);
#else
      *(uint4*)&Ks[pb][(kr0 + (l >> 3)) * 64 + (l & 7) * 8] =
          *(const uint4*)(K + kbase + (size_t)(kt * 128 + kr0 + (l >> 3)) * 1024 + (l & 7) * 8);
#endif
    }
#pragma unroll
    for (int p = 0; p < 4; ++p){
      int dr0 = 16 * w + 4 * p;
#ifdef HAS_GLLDS
      gl_lds16(VT + vbase + (size_t)(dr0 + (l >> 4)) * T_ + kt * 128 + (l & 15) * 8,
               &VTs[pb][dr0 * 128]);
#else
      *(uint4*)&VTs[pb][(dr0 + (l >> 4)) * 128 + (l & 15) * 8] =
          *(const uint4*)(VT + vbase + (size_t)(dr0 + (l >> 4)) * T_ + kt * 128 + (l & 15) * 8);
#endif
    }
  };

  short8 qf[2][2];
#pragma unroll
  for (int mi = 0; mi < 2; ++mi)
#pragma unroll
    for (int s = 0; s < 2; ++s)
      qf[mi][s] = *(const short8*)(Q + kbase + (size_t)(wrow0 + 16 * mi + lr) * 1024 + s * 32 + 8 * lg);

  f32x4 acc[2][4] = {};
  float lsum[2] = {0.f, 0.f};
  const int ktend = qtb;

  STAGE(0, 0);
  __syncthreads();
  for (int kt = 0; kt <= ktend; ++kt){
    const int pb = kt & 1;
    if (kt < ktend) STAGE(kt + 1, pb ^ 1);
    const bool diag = (kt == ktend);
    short8 pf[2][4];
#pragma unroll
    for (int jh = 0; jh < 2; ++jh){
      short8 kf[4][2];
#pragma unroll
      for (int j = 0; j < 4; ++j)
#pragma unroll
        for (int s = 0; s < 2; ++s)
          kf[j][s] = *(const short8*)&Ks[pb][((4 * jh + j) * 16 + lr) * 64 + (((4 * s + lg) ^ (lr & 7)) << 3)];
#pragma unroll
      for (int mi = 0; mi < 2; ++mi){
        f32x4 pr[4];
        float lacc = 0.f;
        const int lim = 32 * w + 16 * mi + lr;
#pragma unroll
        for (int j = 0; j < 4; ++j){
          const int j0 = 4 * jh + j;
          f32x4 z = {};
          z = __builtin_amdgcn_mfma_f32_16x16x32_bf16(kf[j][0], qf[mi][0], z, 0, 0, 0);
          z = __builtin_amdgcn_mfma_f32_16x16x32_bf16(kf[j][1], qf[mi][1], z, 0, 0, 0);
#pragma unroll
          for (int r = 0; r < 4; ++r){
            float e = EXP2(z[r]);
            if (diag && (16 * j0 + 4 * lg + r > lim)) e = 0.f;
            pr[j][r] = e;
            lacc += e;
          }
        }
        lsum[mi] += lacc;
        pf[mi][2 * jh]     = pack8(pr[0], pr[1]);
        pf[mi][2 * jh + 1] = pack8(pr[2], pr[3]);
      }
    }
#pragma unroll
    for (int ks = 0; ks < 4; ++ks)
#pragma unroll
      for (int d0 = 0; d0 < 4; ++d0){
        short8 vf = *(const short8*)&VTs[pb][(d0 * 16 + lr) * 128 + (((4 * ks + lg) ^ (lr & 7)) << 3)];
        acc[0][d0] = __builtin_amdgcn_mfma_f32_16x16x32_bf16(pf[0][ks], vf, acc[0][d0], 0, 0, 0);
        acc[1][d0] = __builtin_amdgcn_mfma_f32_16x16x32_bf16(pf[1][ks], vf, acc[1][d0], 0, 0, 0);
      }
    __syncthreads();
  }

#pragma unroll
  for (int mi = 0; mi < 2; ++mi){
    float v = lsum[mi];
    v += __shfl_xor(v, 16);
    v += __shfl_xor(v, 32);
    float inv = 1.0f / v;
    float invr[4];
#pragma unroll
    for (int r = 0; r < 4; ++r) invr[r] = __shfl(inv, 4 * lg + r);
#pragma unroll
    for (int d0 = 0; d0 < 4; ++d0)
#pragma unroll
      for (int r = 0; r < 4; ++r){
        float ov = acc[mi][d0][r] * invr[r];
        O[kbase + (size_t)(wrow0 + 16 * mi + 4 * lg + r) * 1024 + d0 * 16 + lr] = f2bf(ov);
      }
  }
}

// ---------------- launcher ----------------
extern "C" void kernel_launch(void* const* d_in, const int* in_sizes, int n_in,
                              void* d_out, int out_size, void* d_ws, size_t ws_size,
                              hipStream_t stream)
{
  const float* x  = (const float*)d_in[0];
  const float* Wq = (const float*)d_in[2];
  const float* bq = (const float*)d_in[3];
  const float* Wk = (const float*)d_in[4];
  const float* bk = (const float*)d_in[5];
  const float* Wv = (const float*)d_in[6];
  const float* bv = (const float*)d_in[7];
  const float* Wo = (const float*)d_in[8];
  const float* bo = (const float*)d_in[9];

  char* ws = (char*)d_ws;
  u16* xb  = (u16*)(ws + 0);         // [0,8M)   x bf16; dead after QKV GEMM
  u16* wqb = (u16*)(ws + 8388608);
  u16* wkb = (u16*)(ws + 10485760);
  u16* wvb = (u16*)(ws + 12582912);
  u16* wob = (u16*)(ws + 14680064);
  u16* qb  = (u16*)(ws + 16777216);  // Q pre-scaled
  u16* kb  = (u16*)(ws + 25165824);  // K swizzled
  u16* vb  = (u16*)(ws + 33554432);  // V natural; dead after transpose
  u16* vtb = xb;                     // alias: V^T (128-chunk perm+XOR) after QKV GEMM
  u16* ab  = vb;                     // alias: attention output

  conv_all<<<8192, 256, 0, stream>>>(x, Wq, Wk, Wv, Wo, xb, wqb, wkb, wvb, wob);

  gemm_k6<1><<<dim3(48, 32), 256, 0, stream>>>(
      xb, wqb, wkb, wvb, bq, bk, bv, (void*)qb, (void*)kb, (void*)vb);

  transpose_v128<<<dim3(T_/128, H_, B_), 256, 0, stream>>>(vb, vtb);

  attn_v7<<<dim3(T_/128, H_, B_), 256, 0, stream>>>(qb, kb, vtb, ab);

  gemm_k6<0><<<dim3(16, 32), 256, 0, stream>>>(
      ab, wob, wob, wob, bo, bo, bo, d_out, d_out, d_out);
}

// Round 15
// 115.545 us; speedup vs baseline: 1.0686x; 1.0686x over previous
//
#include <hip/hip_runtime.h>

typedef unsigned short u16;
typedef unsigned int u32;
typedef unsigned long long u64;
typedef __attribute__((ext_vector_type(8))) short short8;
typedef __attribute__((ext_vector_type(4))) float f32x4;

#define B_ 2
#define T_ 2048
#define H_ 16
#define DK_ 64
#define QSCALE 0.18033688011112042f  // 0.125 * log2(e)

__device__ __forceinline__ u16 f2bf(float f){
  unsigned u = __float_as_uint(f);
  return (u16)((u + 0x7fffu + ((u >> 16) & 1u)) >> 16);
}

__device__ __forceinline__ u32 cvtpk(float lo, float hi){
  u32 r;
  asm("v_cvt_pk_bf16_f32 %0, %1, %2" : "=v"(r) : "v"(lo), "v"(hi));
  return r;
}

// 2^x via the compiler's fast-exp path (v_mul+v_exp_f32 WITH proper TRANS-op
// hazard handling — raw inline-asm v_exp_f32 lacks the wait-state and corrupts
// dependent reads; that was round-7's failure).
#define EXP2(x) __expf(0.6931471805599453f * (x))

// pack two f32x4 p-vectors into one bf16 A-fragment (8 elems)
__device__ __forceinline__ short8 pack8(const f32x4 a, const f32x4 b){
  union { u32 u[4]; short8 s; } t;
  t.u[0] = cvtpk(a[0], a[1]); t.u[1] = cvtpk(a[2], a[3]);
  t.u[2] = cvtpk(b[0], b[1]); t.u[3] = cvtpk(b[2], b[3]);
  return t.s;
}

#if defined(__has_builtin)
#if __has_builtin(__builtin_amdgcn_global_load_lds)
#define HAS_GLLDS 1
#endif
#endif

#ifdef HAS_GLLDS
__device__ __forceinline__ void gl_lds16(const u16* g, u16* l){
  __builtin_amdgcn_global_load_lds(
      (__attribute__((address_space(1))) void*)(void*)g,
      (__attribute__((address_space(3))) void*)(void*)l, 16, 0, 0);
}
__device__ __forceinline__ void wait_vm4(){ asm volatile("s_waitcnt vmcnt(4)" ::: "memory"); }
__device__ __forceinline__ void wait_vm0(){ asm volatile("s_waitcnt vmcnt(0)" ::: "memory"); }
__device__ __forceinline__ void pipe_bar(){
  asm volatile("" ::: "memory");
  __builtin_amdgcn_s_barrier();
  asm volatile("" ::: "memory");
}
#else
__device__ __forceinline__ void wait_vm4(){}
__device__ __forceinline__ void wait_vm0(){}
__device__ __forceinline__ void pipe_bar(){ __syncthreads(); }
#endif

// ---------------- fused fp32 -> bf16 convert (x + 4 weights) ----------------
__global__ __launch_bounds__(256) void conv_all(
    const float* __restrict__ x, const float* __restrict__ wq, const float* __restrict__ wk,
    const float* __restrict__ wv, const float* __restrict__ wo,
    u16* __restrict__ xb, u16* __restrict__ wqb, u16* __restrict__ wkb,
    u16* __restrict__ wvb, u16* __restrict__ wob)
{
  int gid = blockIdx.x * 256 + threadIdx.x;
  const float* src; u16* dst; int off;
  if (gid < 1048576){ src = x; dst = xb; off = gid; }
  else {
    int t = gid - 1048576; int s = t >> 18; off = t & 262143;
    src = (s==0)?wq:((s==1)?wk:((s==2)?wv:wo));
    dst = (s==0)?wqb:((s==1)?wkb:((s==2)?wvb:wob));
  }
  float4 v = ((const float4*)src)[off];
  u64 r = (u64)f2bf(v.x) | ((u64)f2bf(v.y)<<16) | ((u64)f2bf(v.z)<<32) | ((u64)f2bf(v.w)<<48);
  ((u64*)dst)[off] = r;
}

// ---------------- GEMM: C[M,1024] = A[M,1024]*W^T + bias ----------------
// 128x128 tile, BK=32, 3-buffer LDS, counted-vmcnt pipeline (prefetch dist 2).
// LDS chunk-swizzle: LDS[row][chunk] holds A[row][chunk ^ ((row>>1)&3)] via
// pre-swizzled per-lane global source (gl_lds dest stays linear, rule #21);
// reads use chunk lg^((lr>>1)&3) -> all 8 lanes of a b128 quarter-group hit
// distinct banks (measured: SQ_LDS_BANK_CONFLICT 3.15M -> 0).
// QKV=1: fused Q/K/V (grid.x=24); Q pre-scaled, K col-swizzled. QKV=0: fp32 out.
template<int QKV>
__global__ __launch_bounds__(256, 3) void gemm_k5(
    const u16* __restrict__ A,
    const u16* __restrict__ W0, const u16* __restrict__ W1, const u16* __restrict__ W2,
    const float* __restrict__ b0, const float* __restrict__ b1, const float* __restrict__ b2,
    void* __restrict__ o0, void* __restrict__ o1, void* __restrict__ o2)
{
  __shared__ u16 As[3 * 4096];
  __shared__ u16 Bs[3 * 4096];
  const int tid = threadIdx.x;
  const int sel = QKV ? (blockIdx.x >> 3) : 0;
  const int n0 = (blockIdx.x & 7) * 128;
  const int m0 = blockIdx.y * 128;
  const u16* Bw = (sel==0)?W0:((sel==1)?W1:W2);
  const float* bias = (sel==0)?b0:((sel==1)?b1:b2);
  const int w = tid>>6, l = tid&63;
  const int lr = l&15, lg = l>>4;
  const int wm = (w&1)*64, wn = (w>>1)*64;
  // staging source: row l>>2 within 16-row chunk, SWIZZLED 16B col chunk
  const int scol = ((l & 3) ^ ((l >> 3) & 3)) * 8;
  const u16* Ab = A  + (size_t)m0*1024 + (size_t)(l>>2)*1024 + scol;
  const u16* Bb = Bw + (size_t)n0*1024 + (size_t)(l>>2)*1024 + scol;
  // read-side swizzle for fragment loads
  const int rsw = (lr >> 1) & 3;
  f32x4 acc[4][4] = {};

  auto STAGE = [&](int t, int pb){
#pragma unroll
    for (int i = 0; i < 2; ++i){
      int c = w*2 + i;
#ifdef HAS_GLLDS
      gl_lds16(Ab + (size_t)(16*c)*1024 + t*32, &As[pb*4096 + c*512]);
      gl_lds16(Bb + (size_t)(16*c)*1024 + t*32, &Bs[pb*4096 + c*512]);
#else
      *(uint4*)&As[pb*4096 + c*512 + l*8] = *(const uint4*)(Ab + (size_t)(16*c)*1024 + t*32);
      *(uint4*)&Bs[pb*4096 + c*512 + l*8] = *(const uint4*)(Bb + (size_t)(16*c)*1024 + t*32);
#endif
    }
  };

  STAGE(0, 0); STAGE(1, 1);
  wait_vm4();
  pipe_bar();
  for (int it = 0; it < 32; ++it){
    const int pb = it % 3;
    if (it < 30) STAGE(it + 2, (it + 2) % 3);
    short8 af[4], bf[4];
#pragma unroll
    for (int mi=0;mi<4;++mi) af[mi] = *(const short8*)&As[pb*4096 + (wm+16*mi+lr)*32 + 8*(lg ^ rsw)];
#pragma unroll
    for (int ni=0;ni<4;++ni) bf[ni] = *(const short8*)&Bs[pb*4096 + (wn+16*ni+lr)*32 + 8*(lg ^ rsw)];
#pragma unroll
    for (int mi=0;mi<4;++mi)
#pragma unroll
      for (int ni=0;ni<4;++ni)
        acc[mi][ni] = __builtin_amdgcn_mfma_f32_16x16x32_bf16(af[mi], bf[ni], acc[mi][ni], 0,0,0);
    if (it < 31){
      if (it < 30) wait_vm4();
      else         wait_vm0();
      pipe_bar();
    }
  }

  float bv[4];
#pragma unroll
  for (int ni=0;ni<4;++ni) bv[ni] = bias[n0+wn+16*ni+lr];
  void* C = QKV ? ((sel==0)?o0:((sel==1)?o1:o2)) : o0;
#pragma unroll
  for (int mi=0;mi<4;++mi)
#pragma unroll
    for (int r=0;r<4;++r){
      const int trow = m0 + wm + 16*mi + 4*lg + r;
#pragma unroll
      for (int ni=0;ni<4;++ni){
        float v = acc[mi][ni][r] + bv[ni];
        int n = n0 + wn + 16*ni + lr;
        if (!QKV){
          ((float*)C)[(size_t)trow*1024 + n] = v;
        } else if (sel == 0){          // Q: pre-scale for exp2 softmax
          ((u16*)C)[(size_t)trow*1024 + n] = f2bf(v * QSCALE);
        } else if (sel == 1){          // K: bank-swizzle dk within each head
          int nsw = (n & ~63) | ((n & 63) ^ ((trow & 7) << 3));
          ((u16*)C)[(size_t)trow*1024 + nsw] = f2bf(v);
        } else {                       // V: natural
          ((u16*)C)[(size_t)trow*1024 + n] = f2bf(v);
        }
      }
    }
}

// ---------------- V transpose: V[B,T,H,DK] -> VT[B,H,DK,T], 128-chunk k-perm + XOR ----
// forward: k = 32ks+16lo+4c+r -> slot = 32ks+8c+4lo+r  (so swapped-QK^T P regs ARE
// the PV A-fragments). inverse: p -> k = 32(p>>5) + 16((p>>2)&1) + 4((p>>3)&3) + (p&3).
// phys: 8-elem chunk index XOR'ed with (d&7) for conflict-free LDS reads.
__global__ __launch_bounds__(256) void transpose_v128(const u16* __restrict__ V,
                                                      u16* __restrict__ VT){
  __shared__ u16 L[128 * 72];
  const int tid = threadIdx.x;
  const int tc = blockIdx.x, h = blockIdx.y, b = blockIdx.z;
#pragma unroll
  for (int p = 0; p < 4; ++p){
    int row = (tid >> 3) + 32 * p, g = tid & 7;
    *(uint4*)&L[row * 72 + g * 8] =
        *(const uint4*)(V + ((size_t)(b * T_ + tc * 128 + row) * H_ + h) * DK_ + g * 8);
  }
  __syncthreads();
#pragma unroll
  for (int p = 0; p < 4; ++p){
    int d = tid >> 2, g8 = (tid & 3) + 4 * p;   // g8 in 0..15
    union { uint4 u; u16 s[8]; } tv;
#pragma unroll
    for (int i = 0; i < 8; ++i){
      int pp = 8 * g8 + i;
      int tl = 32 * (pp >> 5) + 16 * ((pp >> 2) & 1) + 4 * ((pp >> 3) & 3) + (pp & 3);
      tv.s[i] = L[tl * 72 + d];
    }
    *(uint4*)(VT + ((size_t)(b * H_ + h) * DK_ + d) * T_ + tc * 128 + ((8 * g8) ^ ((d & 7) << 3))) = tv.u;
  }
}

// ---------------- causal flash attention: swapped QK^T, reg-P, KVBLK=128 ----------------
// QBLK=128 (4 waves x 32 rows), KVBLK=128: every wave computes every phase (no skip);
// masking confined to the single final diagonal phase. 2-buffer staging + syncthreads.
__global__ __launch_bounds__(256, 2) void attn_v7(
    const u16* __restrict__ Q, const u16* __restrict__ K,
    const u16* __restrict__ VT, u16* __restrict__ O)
{
  __shared__ u16 Ks[2][128 * 64];
  __shared__ u16 VTs[2][64 * 128];
  const int tid = threadIdx.x;
  const int w = tid >> 6, l = tid & 63;
  const int lr = l & 15, lg = l >> 4;
  const int h = blockIdx.y, b = blockIdx.z;
  const int qtb = (b == 0) ? blockIdx.x : (15 - blockIdx.x);  // pair long+short per CU
  const int q0 = qtb * 128;
  const int wrow0 = q0 + 32 * w;
  const size_t kbase = ((size_t)(b * T_) * H_ + h) * DK_;
  const size_t vbase = (size_t)(b * H_ + h) * DK_ * (size_t)T_;

  auto STAGE = [&](int kt, int pb){
#pragma unroll
    for (int p = 0; p < 4; ++p){
      int kr0 = 32 * w + 8 * p;   // 8 K-rows per call (128B rows)
#ifdef HAS_GLLDS
      gl_lds16(K + kbase + (size_t)(kt * 128 + kr0 + (l >> 3)) * 1024 + (l & 7) * 8,
               &Ks[pb][kr0 * 64]);
#else
      *(uint4*)&Ks[pb][(kr0 + (l >> 3)) * 64 + (l & 7) * 8] =
          *(const uint4*)(K + kbase + (size_t)(kt * 128 + kr0 + (l >> 3)) * 1024 + (l & 7) * 8);
#endif
    }
#pragma unroll
    for (int p = 0; p < 4; ++p){
      int dr0 = 16 * w + 4 * p;   // 4 VT d-rows per call (256B rows)
#ifdef HAS_GLLDS
      gl_lds16(VT + vbase + (size_t)(dr0 + (l >> 4)) * T_ + kt * 128 + (l & 15) * 8,
               &VTs[pb][dr0 * 128]);
#else
      *(uint4*)&VTs[pb][(dr0 + (l >> 4)) * 128 + (l & 15) * 8] =
          *(const uint4*)(VT + vbase + (size_t)(dr0 + (l >> 4)) * T_ + kt * 128 + (l & 15) * 8);
#endif
    }
  };

  // Q fragments (pre-scaled): B-operand, rows wrow0+16mi+lr, d-slices s
  short8 qf[2][2];
#pragma unroll
  for (int mi = 0; mi < 2; ++mi)
#pragma unroll
    for (int s = 0; s < 2; ++s)
      qf[mi][s] = *(const short8*)(Q + kbase + (size_t)(wrow0 + 16 * mi + lr) * 1024 + s * 32 + 8 * lg);

  f32x4 acc[2][4] = {};
  float lsum[2] = {0.f, 0.f};
  const int ktend = qtb;

  STAGE(0, 0);
  __syncthreads();
  for (int kt = 0; kt <= ktend; ++kt){
    const int pb = kt & 1;
    if (kt < ktend) STAGE(kt + 1, pb ^ 1);
    const bool diag = (kt == ktend);   // only the final phase masks
    short8 pf[2][4];
#pragma unroll
    for (int jh = 0; jh < 2; ++jh){
      short8 kf[4][2];
#pragma unroll
      for (int j = 0; j < 4; ++j)
#pragma unroll
        for (int s = 0; s < 2; ++s)
          kf[j][s] = *(const short8*)&Ks[pb][((4 * jh + j) * 16 + lr) * 64 + (((4 * s + lg) ^ (lr & 7)) << 3)];
#pragma unroll
      for (int mi = 0; mi < 2; ++mi){
        f32x4 pr[4];
        float lacc = 0.f;
        const int lim = 32 * w + 16 * mi + lr;   // qrow - q0
#pragma unroll
        for (int j = 0; j < 4; ++j){
          const int j0 = 4 * jh + j;
          f32x4 z = {};
          z = __builtin_amdgcn_mfma_f32_16x16x32_bf16(kf[j][0], qf[mi][0], z, 0, 0, 0);
          z = __builtin_amdgcn_mfma_f32_16x16x32_bf16(kf[j][1], qf[mi][1], z, 0, 0, 0);
#pragma unroll
          for (int r = 0; r < 4; ++r){
            float e = EXP2(z[r]);
            if (diag && (16 * j0 + 4 * lg + r > lim)) e = 0.f;
            pr[j][r] = e;
            lacc += e;
          }
        }
        lsum[mi] += lacc;
        pf[mi][2 * jh]     = pack8(pr[0], pr[1]);
        pf[mi][2 * jh + 1] = pack8(pr[2], pr[3]);
      }
    }
    // PV: A = in-register P, B = V^T (matching perm slots, XOR-swizzled phys)
#pragma unroll
    for (int ks = 0; ks < 4; ++ks)
#pragma unroll
      for (int d0 = 0; d0 < 4; ++d0){
        short8 vf = *(const short8*)&VTs[pb][(d0 * 16 + lr) * 128 + (((4 * ks + lg) ^ (lr & 7)) << 3)];
        acc[0][d0] = __builtin_amdgcn_mfma_f32_16x16x32_bf16(pf[0][ks], vf, acc[0][d0], 0, 0, 0);
        acc[1][d0] = __builtin_amdgcn_mfma_f32_16x16x32_bf16(pf[1][ks], vf, acc[1][d0], 0, 0, 0);
      }
    __syncthreads();
  }

  // epilogue: reduce lsum across lg groups, redistribute to acc-row lanes, store
#pragma unroll
  for (int mi = 0; mi < 2; ++mi){
    float v = lsum[mi];
    v += __shfl_xor(v, 16);
    v += __shfl_xor(v, 32);
    float inv = 1.0f / v;     // valid for qrow = wrow0+16mi+lr at every lane
    float invr[4];
#pragma unroll
    for (int r = 0; r < 4; ++r) invr[r] = __shfl(inv, 4 * lg + r);  // provider lane 4lg+r
#pragma unroll
    for (int d0 = 0; d0 < 4; ++d0)
#pragma unroll
      for (int r = 0; r < 4; ++r){
        float ov = acc[mi][d0][r] * invr[r];
        O[kbase + (size_t)(wrow0 + 16 * mi + 4 * lg + r) * 1024 + d0 * 16 + lr] = f2bf(ov);
      }
  }
}

// ---------------- launcher ----------------
extern "C" void kernel_launch(void* const* d_in, const int* in_sizes, int n_in,
                              void* d_out, int out_size, void* d_ws, size_t ws_size,
                              hipStream_t stream)
{
  const float* x  = (const float*)d_in[0];
  const float* Wq = (const float*)d_in[2];
  const float* bq = (const float*)d_in[3];
  const float* Wk = (const float*)d_in[4];
  const float* bk = (const float*)d_in[5];
  const float* Wv = (const float*)d_in[6];
  const float* bv = (const float*)d_in[7];
  const float* Wo = (const float*)d_in[8];
  const float* bo = (const float*)d_in[9];

  char* ws = (char*)d_ws;
  u16* xb  = (u16*)(ws + 0);         // [0,8M)   x bf16; dead after QKV GEMM
  u16* wqb = (u16*)(ws + 8388608);
  u16* wkb = (u16*)(ws + 10485760);
  u16* wvb = (u16*)(ws + 12582912);
  u16* wob = (u16*)(ws + 14680064);
  u16* qb  = (u16*)(ws + 16777216);  // Q pre-scaled
  u16* kb  = (u16*)(ws + 25165824);  // K swizzled
  u16* vb  = (u16*)(ws + 33554432);  // V natural; dead after transpose
  u16* vtb = xb;                     // alias: V^T (128-chunk perm+XOR) after QKV GEMM
  u16* ab  = vb;                     // alias: attention output

  conv_all<<<8192, 256, 0, stream>>>(x, Wq, Wk, Wv, Wo, xb, wqb, wkb, wvb, wob);

  gemm_k5<1><<<dim3(24, 32), 256, 0, stream>>>(
      xb, wqb, wkb, wvb, bq, bk, bv, (void*)qb, (void*)kb, (void*)vb);

  transpose_v128<<<dim3(T_/128, H_, B_), 256, 0, stream>>>(vb, vtb);

  attn_v7<<<dim3(T_/128, H_, B_), 256, 0, stream>>>(qb, kb, vtb, ab);

  gemm_k5<0><<<dim3(8, 32), 256, 0, stream>>>(
      ab, wob, wob, wob, bo, bo, bo, d_out, d_out, d_out);
}